// Round 4
// baseline (164.853 us; speedup 1.0000x reference)
//
#include <hip/hip_runtime.h>
#include <math.h>

// (S,N,B,T,D) = (8,8,2,2048,1024); persistent-pipelined: 512 blocks x 8 bt
#define TPB   256
#define NBLK  512
#define ITERS 8

template <int CTRL>
__device__ __forceinline__ float dpp_add(float x) {
    int yi = __builtin_amdgcn_update_dpp(0, __float_as_int(x), CTRL, 0xF, 0xF, true);
    return x + __int_as_float(yi);
}

// 64-lane sum, pure VALU (no LDS pipe): butterflies + row_bcast chain, total in lane 63.
__device__ __forceinline__ float wave_sum(float x) {
    x = dpp_add<0xB1>(x);    // xor 1
    x = dpp_add<0x4E>(x);    // xor 2
    x = dpp_add<0x141>(x);   // row_half_mirror
    x = dpp_add<0x140>(x);   // row_mirror -> 16-lane row sums
    x = dpp_add<0x142>(x);   // row_bcast15
    x = dpp_add<0x143>(x);   // row_bcast31 -> lane63 = total
    return __int_as_float(__builtin_amdgcn_readlane(__float_as_int(x), 63));
}

__device__ __forceinline__ float dot4(const float4 a, const float4 b) {
    return a.x*b.x + a.y*b.y + a.z*b.z + a.w*b.w;
}

__global__ __launch_bounds__(TPB) void two_phase_attn_kernel(
    const float* __restrict__ q,    // [8][1024]
    const float* __restrict__ V,    // block_reps  [8][2][2048][1024]
    const float* __restrict__ P,    // partial_sums[8][2][2048][1024]
    const float* __restrict__ wgt,  // [1024]
    float* __restrict__ out)        // merged_out | merged_max | merged_lse
{
    constexpr int    N   = 8;
    constexpr int    D   = 1024;
    constexpr int    BT  = 4096;
    constexpr size_t ROW = (size_t)BT * D;
    constexpr size_t OUT_MM  = (size_t)8 * ROW;
    constexpr size_t OUT_LSE = OUT_MM + (size_t)BT * 8;
    constexpr float  SCALE = 0.03125f;
    constexpr float  EPS   = 1e-6f;

    __shared__ float sV[N][D];                  // exactly 32768 B, single buffer

    const int tid  = threadIdx.x;
    const int w    = tid >> 6;
    const int lane = tid & 63;
    const int s0 = 2*w, s1 = s0 + 1;            // wave owns s-pair == n-pair
    const int d0 = lane * 4;
    const int bt0 = blockIdx.x * ITERS;

    const float* Vr0 = V + (size_t)s0*ROW + (size_t)bt0*D + d0;
    const float* Vr1 = V + (size_t)s1*ROW + (size_t)bt0*D + d0;
    const float* Pr0 = P + (size_t)s0*ROW + (size_t)bt0*D + d0;
    const float* Pr1 = P + (size_t)s1*ROW + (size_t)bt0*D + d0;
    float*       Or0 = out + (size_t)s0*ROW + (size_t)bt0*D + d0;
    float*       Or1 = out + (size_t)s1*ROW + (size_t)bt0*D + d0;

    // ---- Prologue: V(bt0) -> regs -> LDS; issue V(bt0+1) -> regs ----
    float4 vst0[4], vst1[4];
    #pragma unroll
    for (int j = 0; j < 4; ++j) {
        vst0[j] = *(const float4*)(Vr0 + j*256);
        vst1[j] = *(const float4*)(Vr1 + j*256);
    }
    #pragma unroll
    for (int j = 0; j < 4; ++j) {
        *(float4*)(&sV[s0][j*256 + d0]) = vst0[j];
        *(float4*)(&sV[s1][j*256 + d0]) = vst1[j];
    }
    #pragma unroll
    for (int j = 0; j < 4; ++j) {
        vst0[j] = *(const float4*)(Vr0 + D + j*256);
        vst1[j] = *(const float4*)(Vr1 + D + j*256);
    }
    __syncthreads();

    for (int k = 0; k < ITERS; ++k) {
        const int off = k * D;

        // ---- Issue P(bt_k) early; ~1500 cyc of dot/reduce work hides it ----
        float4 p0[4], p1[4];
        #pragma unroll
        for (int j = 0; j < 4; ++j) {
            p0[j] = *(const float4*)(Pr0 + off + j*256);
            p1[j] = *(const float4*)(Pr1 + off + j*256);
        }

        // ---- Dots vs all 8 V rows + per-row ssq (j-outer, LDS reads) ----
        float dot0[N], dot1[N], vsq[N];
        #pragma unroll
        for (int n = 0; n < N; ++n) { dot0[n] = 0.f; dot1[n] = 0.f; vsq[n] = 0.f; }
        #pragma unroll
        for (int j = 0; j < 4; ++j) {
            const int d = j*256 + d0;
            const float4 wv = *(const float4*)(wgt + d);
            const float4 a  = *(const float4*)(q + s0*D + d);
            const float4 b  = *(const float4*)(q + s1*D + d);
            const float4 qa = make_float4(a.x*wv.x, a.y*wv.y, a.z*wv.z, a.w*wv.w);
            const float4 qb = make_float4(b.x*wv.x, b.y*wv.y, b.z*wv.z, b.w*wv.w);
            #pragma unroll
            for (int n = 0; n < N; ++n) {
                const float4 v = *(const float4*)(&sV[n][d]);
                dot0[n] += dot4(qa, v);
                dot1[n] += dot4(qb, v);
                vsq[n]  += dot4(v, v);
            }
        }
        #pragma unroll
        for (int n = 0; n < N; ++n) {
            dot0[n] = wave_sum(dot0[n]);
            dot1[n] = wave_sum(dot1[n]);
            vsq[n]  = wave_sum(vsq[n]);
        }

        // ---- Phase 1 softmax (wave-uniform scalars) ----
        float e0[N], e1[N];
        float m0 = -1e30f, m1 = -1e30f;
        #pragma unroll
        for (int n = 0; n < N; ++n) {
            const float rinv = rsqrtf(vsq[n] * (1.0f/1024.0f) + EPS);
            e0[n] = dot0[n] * rinv * SCALE;  m0 = fmaxf(m0, e0[n]);
            e1[n] = dot1[n] * rinv * SCALE;  m1 = fmaxf(m1, e1[n]);
        }
        float es0 = 0.f, es1 = 0.f;
        #pragma unroll
        for (int n = 0; n < N; ++n) {
            e0[n] = __expf(e0[n] - m0);  es0 += e0[n];
            e1[n] = __expf(e1[n] - m1);  es1 += e1[n];
        }

        // ---- Phase 2: rmsnorm(P) dot + merge scalars ----
        float ssq20 = 0.f, ssq21 = 0.f, dp0 = 0.f, dp1 = 0.f;
        #pragma unroll
        for (int j = 0; j < 4; ++j) {
            const int d = j*256 + d0;
            const float4 wv = *(const float4*)(wgt + d);
            const float4 a  = *(const float4*)(q + s0*D + d);
            const float4 b  = *(const float4*)(q + s1*D + d);
            ssq20 += dot4(p0[j], p0[j]);
            ssq21 += dot4(p1[j], p1[j]);
            dp0 += (a.x*wv.x)*p0[j].x + (a.y*wv.y)*p0[j].y + (a.z*wv.z)*p0[j].z + (a.w*wv.w)*p0[j].w;
            dp1 += (b.x*wv.x)*p1[j].x + (b.y*wv.y)*p1[j].y + (b.z*wv.z)*p1[j].z + (b.w*wv.w)*p1[j].w;
        }
        ssq20 = wave_sum(ssq20);  ssq21 = wave_sum(ssq21);
        dp0   = wave_sum(dp0);    dp1   = wave_sum(dp1);

        const float im0 = dp0 * rsqrtf(ssq20 * (1.0f/1024.0f) + EPS) * SCALE;
        const float im1 = dp1 * rsqrtf(ssq21 * (1.0f/1024.0f) + EPS) * SCALE;
        const float mm0 = fmaxf(m0, im0),    mm1 = fmaxf(m1, im1);
        const float wi0 = __expf(m0 - mm0),  wi1 = __expf(m1 - mm1);
        const float wa0 = __expf(im0 - mm0), wa1 = __expf(im1 - mm1);
        const float lse0 = __logf(wi0 * es0 + wa0) + mm0;
        const float lse1 = __logf(wi1 * es1 + wa1) + mm1;
        const float nrm0 = wi0 + wa0,        nrm1 = wi1 + wa1;
        const float cA0 = wi0 / (es0 * nrm0), cA1 = wi1 / (es1 * nrm1);
        const float cp0 = wa0 / nrm0,         cp1 = wa1 / nrm1;

        // ---- Phase E: inter_out from LDS, merge with P, store ----
        #pragma unroll
        for (int j = 0; j < 4; ++j) {
            const int d = j*256 + d0;
            float4 A0 = make_float4(0.f,0.f,0.f,0.f);
            float4 A1 = make_float4(0.f,0.f,0.f,0.f);
            #pragma unroll
            for (int n = 0; n < N; ++n) {
                const float4 v = *(const float4*)(&sV[n][d]);
                A0.x += e0[n]*v.x; A0.y += e0[n]*v.y; A0.z += e0[n]*v.z; A0.w += e0[n]*v.w;
                A1.x += e1[n]*v.x; A1.y += e1[n]*v.y; A1.z += e1[n]*v.z; A1.w += e1[n]*v.w;
            }
            float4 o0, o1;
            o0.x = cA0*A0.x + cp0*p0[j].x;  o0.y = cA0*A0.y + cp0*p0[j].y;
            o0.z = cA0*A0.z + cp0*p0[j].z;  o0.w = cA0*A0.w + cp0*p0[j].w;
            o1.x = cA1*A1.x + cp1*p1[j].x;  o1.y = cA1*A1.y + cp1*p1[j].y;
            o1.z = cA1*A1.z + cp1*p1[j].z;  o1.w = cA1*A1.w + cp1*p1[j].w;
            *(float4*)(Or0 + off + j*256) = o0;
            *(float4*)(Or1 + off + j*256) = o1;
        }
        if (lane == 0) {
            const int bt = bt0 + k;
            out[OUT_MM  + (size_t)s0*BT + bt] = mm0;
            out[OUT_MM  + (size_t)s1*BT + bt] = mm1;
            out[OUT_LSE + (size_t)s0*BT + bt] = lse0;
            out[OUT_LSE + (size_t)s1*BT + bt] = lse1;
        }

        // ---- Pipeline tail: publish V(bt_{k+1}) to LDS, issue V(bt_{k+2}) ----
        __syncthreads();                    // all waves done reading sV
        if (k + 1 < ITERS) {
            #pragma unroll
            for (int j = 0; j < 4; ++j) {
                *(float4*)(&sV[s0][j*256 + d0]) = vst0[j];
                *(float4*)(&sV[s1][j*256 + d0]) = vst1[j];
            }
            if (k + 2 < ITERS) {
                #pragma unroll
                for (int j = 0; j < 4; ++j) {
                    vst0[j] = *(const float4*)(Vr0 + (k+2)*D + j*256);
                    vst1[j] = *(const float4*)(Vr1 + (k+2)*D + j*256);
                }
            }
            __syncthreads();                // sV ready for iter k+1
        }
    }
}

extern "C" void kernel_launch(void* const* d_in, const int* in_sizes, int n_in,
                              void* d_out, int out_size, void* d_ws, size_t ws_size,
                              hipStream_t stream) {
    const float* q   = (const float*)d_in[0];
    const float* V   = (const float*)d_in[1];
    const float* P   = (const float*)d_in[2];
    const float* wgt = (const float*)d_in[3];
    float* o = (float*)d_out;

    two_phase_attn_kernel<<<NBLK, TPB, 0, stream>>>(q, V, P, wgt, o);
}

// Round 5
// 147.350 us; speedup vs baseline: 1.1188x; 1.1188x over previous
//
#include <hip/hip_runtime.h>
#include <math.h>

// (S,N,B,T,D) = (8,8,2,2048,1024)
// One block per (b,t): 512 threads = 8 waves; wave w owns s=w (and stages V row n=w).
#define TPB 512

template <int CTRL>
__device__ __forceinline__ float dpp_add(float x) {
    int yi = __builtin_amdgcn_update_dpp(0, __float_as_int(x), CTRL, 0xF, 0xF, true);
    return x + __int_as_float(yi);
}

// 64-lane sum, pure VALU (no LDS pipe): butterflies + row_bcast chain, total in lane 63.
__device__ __forceinline__ float wave_sum(float x) {
    x = dpp_add<0xB1>(x);    // xor 1
    x = dpp_add<0x4E>(x);    // xor 2
    x = dpp_add<0x141>(x);   // row_half_mirror
    x = dpp_add<0x140>(x);   // row_mirror -> 16-lane row sums
    x = dpp_add<0x142>(x);   // row_bcast15
    x = dpp_add<0x143>(x);   // row_bcast31 -> lane63 = total
    return __int_as_float(__builtin_amdgcn_readlane(__float_as_int(x), 63));
}

__device__ __forceinline__ float dot4(const float4 a, const float4 b) {
    return a.x*b.x + a.y*b.y + a.z*b.z + a.w*b.w;
}

__global__ __launch_bounds__(TPB, 8) void two_phase_attn_kernel(
    const float* __restrict__ q,    // [8][1024]
    const float* __restrict__ V,    // block_reps  [8][2][2048][1024]
    const float* __restrict__ P,    // partial_sums[8][2][2048][1024]
    const float* __restrict__ wgt,  // [1024]
    float* __restrict__ out)        // merged_out | merged_max | merged_lse
{
    constexpr int    N   = 8;
    constexpr int    D   = 1024;
    constexpr int    BT  = 4096;
    constexpr size_t ROW = (size_t)BT * D;
    constexpr size_t OUT_MM  = (size_t)8 * ROW;
    constexpr size_t OUT_LSE = OUT_MM + (size_t)BT * 8;
    constexpr float  SCALE = 0.03125f;
    constexpr float  EPS   = 1e-6f;

    __shared__ float sV[N][D];      // 32 KB
    __shared__ float sSsq[N];

    const int tid  = threadIdx.x;
    const int w    = tid >> 6;      // wave id == s index == staged V row
    const int lane = tid & 63;
    const int d0   = lane * 4;
    const int bt   = blockIdx.x;
    const size_t btD = (size_t)bt * D;

    const float* Vr = V   + (size_t)w * ROW + btD + d0;
    const float* Pr = P   + (size_t)w * ROW + btD + d0;
    float*       Or = out + (size_t)w * ROW + btD + d0;

    // ---- Issue all global loads up front (16 independent float4 in flight) ----
    float4 v[4], p[4], qw[4];
    #pragma unroll
    for (int j = 0; j < 4; ++j) v[j] = *(const float4*)(Vr + j*256);
    #pragma unroll
    for (int j = 0; j < 4; ++j) p[j] = *(const float4*)(Pr + j*256);
    #pragma unroll
    for (int j = 0; j < 4; ++j) {
        const int d = j*256 + d0;
        const float4 a  = *(const float4*)(q + w*D + d);
        const float4 wv = *(const float4*)(wgt + d);
        qw[j] = make_float4(a.x*wv.x, a.y*wv.y, a.z*wv.z, a.w*wv.w);
    }

    // ---- Stage own V row to LDS; ssq from registers; one barrier ----
    float vsq = 0.f;
    #pragma unroll
    for (int j = 0; j < 4; ++j) {
        *(float4*)(&sV[w][j*256 + d0]) = v[j];
        vsq += dot4(v[j], v[j]);
    }
    vsq = wave_sum(vsq);
    if (lane == 0) sSsq[w] = vsq;
    __syncthreads();

    // ---- Dots: own q*w vs all 8 V rows (LDS) ----
    float dt[N];
    #pragma unroll
    for (int n = 0; n < N; ++n) dt[n] = 0.f;
    #pragma unroll
    for (int j = 0; j < 4; ++j) {
        const int d = j*256 + d0;
        #pragma unroll
        for (int n = 0; n < N; ++n)
            dt[n] += dot4(qw[j], *(const float4*)(&sV[n][d]));
    }
    #pragma unroll
    for (int n = 0; n < N; ++n) dt[n] = wave_sum(dt[n]);

    // ---- Phase 1 softmax over n (wave-uniform scalars; dt -> exp weights) ----
    float m = -1e30f;
    #pragma unroll
    for (int n = 0; n < N; ++n) {
        const float rinv = rsqrtf(sSsq[n] * (1.0f/1024.0f) + EPS);
        dt[n] = dt[n] * rinv * SCALE;
        m = fmaxf(m, dt[n]);
    }
    float es = 0.f;
    #pragma unroll
    for (int n = 0; n < N; ++n) { dt[n] = __expf(dt[n] - m); es += dt[n]; }

    // ---- Phase 2: rmsnorm(P) dot + merge scalars ----
    float ssq2 = 0.f, dp = 0.f;
    #pragma unroll
    for (int j = 0; j < 4; ++j) {
        ssq2 += dot4(p[j], p[j]);
        dp   += dot4(qw[j], p[j]);
    }
    ssq2 = wave_sum(ssq2);
    dp   = wave_sum(dp);

    const float im  = dp * rsqrtf(ssq2 * (1.0f/1024.0f) + EPS) * SCALE;
    const float mm  = fmaxf(m, im);
    const float wi  = __expf(m  - mm);
    const float wa  = __expf(im - mm);
    const float lse = __logf(wi * es + wa) + mm;   // exp(inter_lse-inter_max)==es
    const float nrm = wi + wa;
    const float cA  = wi / (es * nrm);
    const float cp  = wa / nrm;

    // ---- Phase E: inter_out from LDS, merge with P, store ----
    #pragma unroll
    for (int j = 0; j < 4; ++j) {
        const int d = j*256 + d0;
        float4 A = make_float4(0.f, 0.f, 0.f, 0.f);
        #pragma unroll
        for (int n = 0; n < N; ++n) {
            const float4 vv = *(const float4*)(&sV[n][d]);
            A.x += dt[n]*vv.x; A.y += dt[n]*vv.y; A.z += dt[n]*vv.z; A.w += dt[n]*vv.w;
        }
        float4 o;
        o.x = cA*A.x + cp*p[j].x;
        o.y = cA*A.y + cp*p[j].y;
        o.z = cA*A.z + cp*p[j].z;
        o.w = cA*A.w + cp*p[j].w;
        *(float4*)(Or + j*256) = o;
    }
    if (lane == 0) {
        out[OUT_MM  + (size_t)w * BT + bt] = mm;
        out[OUT_LSE + (size_t)w * BT + bt] = lse;
    }
}

extern "C" void kernel_launch(void* const* d_in, const int* in_sizes, int n_in,
                              void* d_out, int out_size, void* d_ws, size_t ws_size,
                              hipStream_t stream) {
    const float* q   = (const float*)d_in[0];   // pseudo_queries [8,1024]
    const float* V   = (const float*)d_in[1];   // block_reps     [8,2,2048,1024]
    const float* P   = (const float*)d_in[2];   // partial_sums   [8,2,2048,1024]
    const float* wgt = (const float*)d_in[3];   // norm_weight    [1024]
    float* o = (float*)d_out;

    two_phase_attn_kernel<<<4096, TPB, 0, stream>>>(q, V, P, wgt, o);
}

// Round 6
// 141.106 us; speedup vs baseline: 1.1683x; 1.0443x over previous
//
#include <hip/hip_runtime.h>
#include <math.h>

// (S,N,B,T,D) = (8,8,2,2048,1024)
// Block = (s-pair, bt). 256 threads; thread owns float4 d-chunk d0 = tid*4.
// All 8 V-row chunks live in registers; no LDS V staging at all.
// Same-bt blocks adjacent in dispatch => V shared via L2/L3, read once from HBM.
#define TPB 256

template <int CTRL>
__device__ __forceinline__ float dpp_add(float x) {
    int yi = __builtin_amdgcn_update_dpp(0, __float_as_int(x), CTRL, 0xF, 0xF, true);
    return x + __int_as_float(yi);
}

// 64-lane sum, pure VALU: butterflies + row_bcast chain; total broadcast from lane 63.
__device__ __forceinline__ float wave_sum(float x) {
    x = dpp_add<0xB1>(x);    // xor 1
    x = dpp_add<0x4E>(x);    // xor 2
    x = dpp_add<0x141>(x);   // row_half_mirror
    x = dpp_add<0x140>(x);   // row_mirror -> 16-lane row sums
    x = dpp_add<0x142>(x);   // row_bcast15
    x = dpp_add<0x143>(x);   // row_bcast31 -> lane63 = total
    return __int_as_float(__builtin_amdgcn_readlane(__float_as_int(x), 63));
}

__device__ __forceinline__ float dot4(const float4 a, const float4 b) {
    return a.x*b.x + a.y*b.y + a.z*b.z + a.w*b.w;
}

__global__ __launch_bounds__(TPB, 4) void two_phase_attn_kernel(
    const float* __restrict__ q,    // [8][1024]
    const float* __restrict__ V,    // block_reps  [8][2][2048][1024]
    const float* __restrict__ P,    // partial_sums[8][2][2048][1024]
    const float* __restrict__ wgt,  // [1024]
    float* __restrict__ out)        // merged_out | merged_max | merged_lse
{
    constexpr int    N   = 8;
    constexpr int    BT  = 4096;
    constexpr int    D   = 1024;
    constexpr size_t ROW = (size_t)BT * D;
    constexpr size_t OUT_MM  = (size_t)8 * ROW;
    constexpr size_t OUT_LSE = OUT_MM + (size_t)BT * 8;
    constexpr float  SCALE = 0.03125f;
    constexpr float  EPS   = 1e-6f;

    __shared__ float red[28][4];    // cross-wave partials (448 B)

    const int tid  = threadIdx.x;
    const int w    = tid >> 6;
    const int lane = tid & 63;
    const int idx  = blockIdx.x;
    const int bt   = idx >> 2;      // same-bt blocks adjacent -> L2/L3 V sharing
    const int sp   = idx & 3;
    const int s0   = 2*sp, s1 = 2*sp + 1;
    const int d0   = tid * 4;
    const size_t btD = (size_t)bt * D;

    // ---- All global loads issued up front (13 independent float4 per thread) ----
    float4 v[N];
    #pragma unroll
    for (int n = 0; n < N; ++n)
        v[n] = *(const float4*)(V + (size_t)n * ROW + btD + d0);
    const float4 p0 = *(const float4*)(P + (size_t)s0 * ROW + btD + d0);
    const float4 p1 = *(const float4*)(P + (size_t)s1 * ROW + btD + d0);
    const float4 a0 = *(const float4*)(q + s0 * D + d0);
    const float4 a1 = *(const float4*)(q + s1 * D + d0);
    const float4 wv = *(const float4*)(wgt + d0);
    const float4 qw0 = make_float4(a0.x*wv.x, a0.y*wv.y, a0.z*wv.z, a0.w*wv.w);
    const float4 qw1 = make_float4(a1.x*wv.x, a1.y*wv.y, a1.z*wv.z, a1.w*wv.w);

    // ---- Per-thread partials: 28 scalars ----
    // layout: r[0..7]=dot(qw0,V[n]), r[8..15]=dot(qw1,V[n]), r[16..23]=vsq[n],
    //         r[24]=ssq(P0), r[25]=ssq(P1), r[26]=dot(qw0,P0), r[27]=dot(qw1,P1)
    float r[28];
    #pragma unroll
    for (int n = 0; n < N; ++n) {
        r[n]      = dot4(qw0, v[n]);
        r[8 + n]  = dot4(qw1, v[n]);
        r[16 + n] = dot4(v[n], v[n]);
    }
    r[24] = dot4(p0, p0);
    r[25] = dot4(p1, p1);
    r[26] = dot4(qw0, p0);
    r[27] = dot4(qw1, p1);

    // ---- Wave reduce (pure VALU), then tiny LDS cross-wave exchange ----
    #pragma unroll
    for (int i = 0; i < 28; ++i) r[i] = wave_sum(r[i]);
    if (lane == 0) {
        #pragma unroll
        for (int i = 0; i < 28; ++i) red[i][w] = r[i];
    }
    __syncthreads();
    #pragma unroll
    for (int i = 0; i < 28; ++i) {
        const float4 t = *(const float4*)(&red[i][0]);   // uniform addr: broadcast
        r[i] = t.x + t.y + t.z + t.w;
    }

    // ---- Phase 1 softmax over n (wave-uniform scalars) ----
    float e0[N], e1[N];
    float m0 = -1e30f, m1 = -1e30f;
    #pragma unroll
    for (int n = 0; n < N; ++n) {
        const float rinv = rsqrtf(r[16 + n] * (1.0f/1024.0f) + EPS);
        e0[n] = r[n]     * rinv * SCALE;  m0 = fmaxf(m0, e0[n]);
        e1[n] = r[8 + n] * rinv * SCALE;  m1 = fmaxf(m1, e1[n]);
    }
    float es0 = 0.f, es1 = 0.f;
    #pragma unroll
    for (int n = 0; n < N; ++n) {
        e0[n] = __expf(e0[n] - m0);  es0 += e0[n];
        e1[n] = __expf(e1[n] - m1);  es1 += e1[n];
    }

    // ---- Phase 2 merge scalars ----
    const float im0 = r[26] * rsqrtf(r[24] * (1.0f/1024.0f) + EPS) * SCALE;
    const float im1 = r[27] * rsqrtf(r[25] * (1.0f/1024.0f) + EPS) * SCALE;
    const float mm0 = fmaxf(m0, im0),    mm1 = fmaxf(m1, im1);
    const float wi0 = __expf(m0 - mm0),  wi1 = __expf(m1 - mm1);
    const float wa0 = __expf(im0 - mm0), wa1 = __expf(im1 - mm1);
    const float lse0 = __logf(wi0 * es0 + wa0) + mm0;   // exp(inter_lse-inter_max)==es
    const float lse1 = __logf(wi1 * es1 + wa1) + mm1;
    const float nrm0 = wi0 + wa0,         nrm1 = wi1 + wa1;
    const float cA0 = wi0 / (es0 * nrm0), cA1 = wi1 / (es1 * nrm1);
    const float cp0 = wa0 / nrm0,         cp1 = wa1 / nrm1;

    // ---- Phase E: inter_out from register-resident V; merge; store ----
    float4 A0 = make_float4(0.f,0.f,0.f,0.f);
    float4 A1 = make_float4(0.f,0.f,0.f,0.f);
    #pragma unroll
    for (int n = 0; n < N; ++n) {
        A0.x += e0[n]*v[n].x; A0.y += e0[n]*v[n].y; A0.z += e0[n]*v[n].z; A0.w += e0[n]*v[n].w;
        A1.x += e1[n]*v[n].x; A1.y += e1[n]*v[n].y; A1.z += e1[n]*v[n].z; A1.w += e1[n]*v[n].w;
    }
    float4 o0, o1;
    o0.x = cA0*A0.x + cp0*p0.x;  o0.y = cA0*A0.y + cp0*p0.y;
    o0.z = cA0*A0.z + cp0*p0.z;  o0.w = cA0*A0.w + cp0*p0.w;
    o1.x = cA1*A1.x + cp1*p1.x;  o1.y = cA1*A1.y + cp1*p1.y;
    o1.z = cA1*A1.z + cp1*p1.z;  o1.w = cA1*A1.w + cp1*p1.w;
    *(float4*)(out + (size_t)s0 * ROW + btD + d0) = o0;
    *(float4*)(out + (size_t)s1 * ROW + btD + d0) = o1;

    if (tid == 0) {
        out[OUT_MM  + (size_t)s0 * BT + bt] = mm0;
        out[OUT_MM  + (size_t)s1 * BT + bt] = mm1;
        out[OUT_LSE + (size_t)s0 * BT + bt] = lse0;
        out[OUT_LSE + (size_t)s1 * BT + bt] = lse1;
    }
}

extern "C" void kernel_launch(void* const* d_in, const int* in_sizes, int n_in,
                              void* d_out, int out_size, void* d_ws, size_t ws_size,
                              hipStream_t stream) {
    const float* q   = (const float*)d_in[0];   // pseudo_queries [8,1024]
    const float* V   = (const float*)d_in[1];   // block_reps     [8,2,2048,1024]
    const float* P   = (const float*)d_in[2];   // partial_sums   [8,2,2048,1024]
    const float* wgt = (const float*)d_in[3];   // norm_weight    [1024]
    float* o = (float*)d_out;

    two_phase_attn_kernel<<<4096 * 4, TPB, 0, stream>>>(q, V, P, wgt, o);
}

// Round 7
// 92.656 us; speedup vs baseline: 1.7792x; 1.5229x over previous
//
#include <hip/hip_runtime.h>
#include <math.h>

// (S,N,B,T,D) = (8,8,2,2048,1024)
// Grid 8192 = (xcd 8) x (k 1024); xcd owns btp range [xcd*256, xcd*256+256);
// k%4 = sp (s-pair). 4 same-btp blocks consecutive on one XCD => V L2-hot.
// Block: 256 thr = 4 waves. Waves 0,1 -> bt_a (j{0,1}/{2,3}); waves 2,3 -> bt_b.
// All 8 V-row chunks register-resident; LDS only for a 448 B partial exchange.
#define TPB 256

template <int CTRL>
__device__ __forceinline__ float dpp_add(float x) {
    int yi = __builtin_amdgcn_update_dpp(0, __float_as_int(x), CTRL, 0xF, 0xF, true);
    return x + __int_as_float(yi);
}

// 64-lane sum, pure VALU: butterflies + row_bcast chain; total broadcast from lane 63.
__device__ __forceinline__ float wave_sum(float x) {
    x = dpp_add<0xB1>(x);    // xor 1
    x = dpp_add<0x4E>(x);    // xor 2
    x = dpp_add<0x141>(x);   // row_half_mirror
    x = dpp_add<0x140>(x);   // row_mirror -> 16-lane row sums
    x = dpp_add<0x142>(x);   // row_bcast15
    x = dpp_add<0x143>(x);   // row_bcast31 -> lane63 = total
    return __int_as_float(__builtin_amdgcn_readlane(__float_as_int(x), 63));
}

__device__ __forceinline__ float dot4(const float4 a, const float4 b) {
    return a.x*b.x + a.y*b.y + a.z*b.z + a.w*b.w;
}

__global__ __launch_bounds__(TPB, 3) void two_phase_attn_kernel(
    const float* __restrict__ q,    // [8][1024]
    const float* __restrict__ V,    // block_reps  [8][2][2048][1024]
    const float* __restrict__ P,    // partial_sums[8][2][2048][1024]
    const float* __restrict__ wgt,  // [1024]
    float* __restrict__ out)        // merged_out | merged_max | merged_lse
{
    constexpr int    N   = 8;
    constexpr int    BT  = 4096;
    constexpr int    D   = 1024;
    constexpr size_t ROW = (size_t)BT * D;
    constexpr size_t OUT_MM  = (size_t)8 * ROW;
    constexpr size_t OUT_LSE = OUT_MM + (size_t)BT * 8;
    constexpr float  SCALE = 0.03125f;
    constexpr float  EPS   = 1e-6f;

    __shared__ float red[4][28];    // per-wave partial sums (448 B)

    const int tid  = threadIdx.x;
    const int w    = tid >> 6;
    const int lane = tid & 63;

    // XCD-aware decomposition (dispatch: blockIdx % 8 -> XCD)
    const int b   = blockIdx.x;
    const int xcd = b & 7;
    const int k   = b >> 3;               // 0..1023, launch order within XCD
    const int btp = xcd * 256 + (k >> 2); // bt-pair, contiguous per XCD
    const int sp  = k & 3;
    const int s0  = 2 * sp, s1 = s0 + 1;

    const int bt    = 2 * btp + (w >> 1); // waves 0,1 -> bt_a; 2,3 -> bt_b
    const int d0    = (w & 1) * 512 + lane * 4;  // chunks at d0 and d0+256
    const size_t btD = (size_t)bt * D;

    // ---- All global loads issued up front (26 independent float4/thread) ----
    float4 v[N][2];
    #pragma unroll
    for (int n = 0; n < N; ++n) {
        v[n][0] = *(const float4*)(V + (size_t)n * ROW + btD + d0);
        v[n][1] = *(const float4*)(V + (size_t)n * ROW + btD + d0 + 256);
    }
    float4 p0[2], p1[2];
    p0[0] = *(const float4*)(P + (size_t)s0 * ROW + btD + d0);
    p0[1] = *(const float4*)(P + (size_t)s0 * ROW + btD + d0 + 256);
    p1[0] = *(const float4*)(P + (size_t)s1 * ROW + btD + d0);
    p1[1] = *(const float4*)(P + (size_t)s1 * ROW + btD + d0 + 256);

    float4 qw0[2], qw1[2];
    #pragma unroll
    for (int c = 0; c < 2; ++c) {
        const int d = d0 + c * 256;
        const float4 a0 = *(const float4*)(q + s0 * D + d);
        const float4 a1 = *(const float4*)(q + s1 * D + d);
        const float4 wv = *(const float4*)(wgt + d);
        qw0[c] = make_float4(a0.x*wv.x, a0.y*wv.y, a0.z*wv.z, a0.w*wv.w);
        qw1[c] = make_float4(a1.x*wv.x, a1.y*wv.y, a1.z*wv.z, a1.w*wv.w);
    }

    // ---- Per-thread partials (28 scalars over the thread's 8 floats) ----
    // r[0..7]=dot(qw0,V[n]) r[8..15]=dot(qw1,V[n]) r[16..23]=vsq[n]
    // r[24]=ssq(P0) r[25]=ssq(P1) r[26]=dot(qw0,P0) r[27]=dot(qw1,P1)
    float r[28];
    #pragma unroll
    for (int n = 0; n < N; ++n) {
        r[n]      = dot4(qw0[0], v[n][0]) + dot4(qw0[1], v[n][1]);
        r[8 + n]  = dot4(qw1[0], v[n][0]) + dot4(qw1[1], v[n][1]);
        r[16 + n] = dot4(v[n][0], v[n][0]) + dot4(v[n][1], v[n][1]);
    }
    r[24] = dot4(p0[0], p0[0]) + dot4(p0[1], p0[1]);
    r[25] = dot4(p1[0], p1[0]) + dot4(p1[1], p1[1]);
    r[26] = dot4(qw0[0], p0[0]) + dot4(qw0[1], p0[1]);
    r[27] = dot4(qw1[0], p1[0]) + dot4(qw1[1], p1[1]);

    // ---- Wave reduce (28 independent DPP chains), 2-wave LDS exchange ----
    #pragma unroll
    for (int i = 0; i < 28; ++i) r[i] = wave_sum(r[i]);
    if (lane < 28) red[w][lane] = r[lane];   // r uniform; lane i writes r[i]... 
    __syncthreads();
    {
        const int wp = w ^ 1;                 // partner wave (same bt)
        #pragma unroll
        for (int i = 0; i < 28; ++i) r[i] += red[wp][i];   // uniform: broadcast
    }

    // ---- Phase 1 softmax over n (wave-uniform scalars) ----
    float e0[N], e1[N];
    float m0 = -1e30f, m1 = -1e30f;
    #pragma unroll
    for (int n = 0; n < N; ++n) {
        const float rinv = rsqrtf(r[16 + n] * (1.0f/1024.0f) + EPS);
        e0[n] = r[n]     * rinv * SCALE;  m0 = fmaxf(m0, e0[n]);
        e1[n] = r[8 + n] * rinv * SCALE;  m1 = fmaxf(m1, e1[n]);
    }
    float es0 = 0.f, es1 = 0.f;
    #pragma unroll
    for (int n = 0; n < N; ++n) {
        e0[n] = __expf(e0[n] - m0);  es0 += e0[n];
        e1[n] = __expf(e1[n] - m1);  es1 += e1[n];
    }

    // ---- Phase 2 merge scalars ----
    const float im0 = r[26] * rsqrtf(r[24] * (1.0f/1024.0f) + EPS) * SCALE;
    const float im1 = r[27] * rsqrtf(r[25] * (1.0f/1024.0f) + EPS) * SCALE;
    const float mm0 = fmaxf(m0, im0),    mm1 = fmaxf(m1, im1);
    const float wi0 = __expf(m0 - mm0),  wi1 = __expf(m1 - mm1);
    const float wa0 = __expf(im0 - mm0), wa1 = __expf(im1 - mm1);
    const float lse0 = __logf(wi0 * es0 + wa0) + mm0;   // exp(inter_lse-inter_max)==es
    const float lse1 = __logf(wi1 * es1 + wa1) + mm1;
    const float nrm0 = wi0 + wa0,         nrm1 = wi1 + wa1;
    const float cA0 = wi0 / (es0 * nrm0), cA1 = wi1 / (es1 * nrm1);
    const float cp0 = wa0 / nrm0,         cp1 = wa1 / nrm1;

    // ---- Phase E: inter_out from register-resident V; merge; store ----
    #pragma unroll
    for (int c = 0; c < 2; ++c) {
        float4 A0 = make_float4(0.f,0.f,0.f,0.f);
        float4 A1 = make_float4(0.f,0.f,0.f,0.f);
        #pragma unroll
        for (int n = 0; n < N; ++n) {
            const float4 vv = v[n][c];
            A0.x += e0[n]*vv.x; A0.y += e0[n]*vv.y; A0.z += e0[n]*vv.z; A0.w += e0[n]*vv.w;
            A1.x += e1[n]*vv.x; A1.y += e1[n]*vv.y; A1.z += e1[n]*vv.z; A1.w += e1[n]*vv.w;
        }
        const float4 pc0 = p0[c], pc1 = p1[c];
        float4 o0, o1;
        o0.x = cA0*A0.x + cp0*pc0.x;  o0.y = cA0*A0.y + cp0*pc0.y;
        o0.z = cA0*A0.z + cp0*pc0.z;  o0.w = cA0*A0.w + cp0*pc0.w;
        o1.x = cA1*A1.x + cp1*pc1.x;  o1.y = cA1*A1.y + cp1*pc1.y;
        o1.z = cA1*A1.z + cp1*pc1.z;  o1.w = cA1*A1.w + cp1*pc1.w;
        *(float4*)(out + (size_t)s0 * ROW + btD + d0 + c*256) = o0;
        *(float4*)(out + (size_t)s1 * ROW + btD + d0 + c*256) = o1;
    }
    if ((w & 1) == 0 && lane == 0) {      // one wave per bt writes stats
        out[OUT_MM  + (size_t)s0 * BT + bt] = mm0;
        out[OUT_MM  + (size_t)s1 * BT + bt] = mm1;
        out[OUT_LSE + (size_t)s0 * BT + bt] = lse0;
        out[OUT_LSE + (size_t)s1 * BT + bt] = lse1;
    }
}

extern "C" void kernel_launch(void* const* d_in, const int* in_sizes, int n_in,
                              void* d_out, int out_size, void* d_ws, size_t ws_size,
                              hipStream_t stream) {
    const float* q   = (const float*)d_in[0];   // pseudo_queries [8,1024]
    const float* V   = (const float*)d_in[1];   // block_reps     [8,2,2048,1024]
    const float* P   = (const float*)d_in[2];   // partial_sums   [8,2,2048,1024]
    const float* wgt = (const float*)d_in[3];   // norm_weight    [1024]
    float* o = (float*)d_out;

    two_phase_attn_kernel<<<8192, TPB, 0, stream>>>(q, V, P, wgt, o);
}